// Round 12
// baseline (424.813 us; speedup 1.0000x reference)
//
#include <hip/hip_runtime.h>

typedef __attribute__((ext_vector_type(8))) short bf16x8;
typedef __attribute__((ext_vector_type(4))) float f32x4;

constexpr int NCH = 18;     // 32-k chunks per K-quarter (K = 2304 symmetrized)
constexpr int REPS = 8;     // profiling repetitions (probe round)

__device__ __forceinline__ unsigned short bf_rne(float f) {
  unsigned u = __float_as_uint(f);
  return (unsigned short)((u + 0x7fffu + ((u >> 16) & 1u)) >> 16);
}

// ---- prepass: symmetrize + pack W fragment-linear (verbatim r5/r8, verified) ----
__global__ __launch_bounds__(256) void wprep_kernel(const float* __restrict__ W,
                                                    unsigned short* __restrict__ Wp) {
  int e = blockIdx.x * 256 + threadIdx.x;   // 576*256 = 147456
  int c = e & 2047;
  int t2 = e >> 11;
  int kq = t2 / 18;
  int j = t2 - kq * 18;
  int nt = c >> 9;
  int q = (c >> 7) & 3;
  int r16 = (c >> 3) & 15;
  int el = c & 7;
  int o = nt * 16 + r16;
  int kl = j * 32 + q * 8 + el;
  int jblk = kl >> 6, i = kl & 63;
  int run1 = 8 - kq;
  int G, F;
  if (jblk < run1) { G = 7 - kq; F = jblk; } else { G = kq; F = jblk - run1; }
  int f = F * 8 + (i >> 3), g = G * 8 + (i & 7);
  float v = W[o * 4096 + f * 64 + g];
  if (F != G) v += W[o * 4096 + g * 64 + f];
  Wp[e] = bf_rne(v);
}

// ---- PROBE quad: r8 body x REPS (rep loop kept live via asm keep-alive). ----
// Last rep's acc feeds the real epilogue -> output is exactly r8's.
__global__ __launch_bounds__(512, 2) void quad_rep(const float* __restrict__ x,
                                                   const unsigned short* __restrict__ Wp,
                                                   float* __restrict__ out) {
  __shared__ float xT[8192];                 // [f 64][px 128], word = f*128 + (px^f)
  __shared__ alignas(16) float red[16384];   // 16 regions x 4 KB

  const int t = threadIdx.x;
  const int lane = t & 63;
  const int wv = t >> 6;
  const int kq = wv & 3;
  const int ph = wv >> 2;
  const int q = lane >> 4;
  const int r16 = lane & 15;
  const int pxbase = blockIdx.x * 128;

  const char* wsrc = reinterpret_cast<const char*>(Wp) + kq * 73728 + lane * 16;
  const int run1 = 8 - kq;

  bf16x8 bufs[4][4];
  auto loadB = [&](int j, int slot) {
#pragma unroll
    for (int nt = 0; nt < 4; ++nt)
      bufs[slot][nt] = *reinterpret_cast<const bf16x8*>(wsrc + j * 4096 + nt * 1024);
  };

  float xg[4][8];
  auto load_xg = [&](int G) {
#pragma unroll
    for (int m = 0; m < 4; ++m) {
      int px = ph * 64 + m * 16 + r16;
#pragma unroll
      for (int b = 0; b < 8; ++b) {
        int row = G * 8 + b;
        xg[m][b] = xT[row * 128 + (px ^ row)];
      }
    }
  };

  f32x4 acc[4][4];

#pragma unroll 1
  for (int rep = 0; rep < REPS; ++rep) {
    loadB(0, 0); loadB(1, 1); loadB(2, 2);

    // x tile -> xT (per rep, mirroring one full dispatch's staging cost)
    {
      const float* xg_ = x + (long)pxbase * 64;
#pragma unroll
      for (int c = 0; c < 4; ++c) {
        int e4 = c * 512 + t;
        int px = e4 >> 4;
        int f0 = (e4 & 15) * 4;
        float4 v = *reinterpret_cast<const float4*>(xg_ + e4 * 4);
        xT[(f0 + 0) * 128 + (px ^ (f0 + 0))] = v.x;
        xT[(f0 + 1) * 128 + (px ^ (f0 + 1))] = v.y;
        xT[(f0 + 2) * 128 + (px ^ (f0 + 2))] = v.z;
        xT[(f0 + 3) * 128 + (px ^ (f0 + 3))] = v.w;
      }
    }
    __syncthreads();

    load_xg(7 - kq);
#pragma unroll
    for (int m = 0; m < 4; ++m)
#pragma unroll
      for (int nt = 0; nt < 4; ++nt)
        acc[m][nt] = f32x4{0.f, 0.f, 0.f, 0.f};

#pragma unroll
    for (int j = 0; j < NCH; ++j) {
      if (j + 3 < NCH) loadB(j + 3, (j + 3) & 3);
      if (j == 2 * run1) load_xg(kq);
      const int s = j & 1;
      const int blk = j >> 1;
      const int F = (blk < run1) ? blk : blk - run1;
      const int row = F * 8 + s * 4 + q;
      const int slot = j & 3;
      bf16x8 afr[4];
#pragma unroll
      for (int m = 0; m < 4; ++m) {
        float xf = xT[row * 128 + ((ph * 64 + m * 16 + r16) ^ row)];
        union { unsigned u[4]; bf16x8 v; } pk;
#pragma unroll
        for (int i = 0; i < 4; ++i) {
          unsigned p0 = __float_as_uint(xf * xg[m][2 * i]);
          unsigned p1 = __float_as_uint(xf * xg[m][2 * i + 1]);
          pk.u[i] = __builtin_amdgcn_perm(p1, p0, 0x07060302u);
        }
        afr[m] = pk.v;
      }
#pragma unroll
      for (int nt = 0; nt < 4; ++nt)
#pragma unroll
        for (int m = 0; m < 4; ++m)
          acc[m][nt] = __builtin_amdgcn_mfma_f32_16x16x32_bf16(afr[m], bufs[slot][nt],
                                                               acc[m][nt], 0, 0, 0);
    }

    // keep-alive: prevents DCE of reps 0..REPS-2 (values pass through unchanged)
#pragma unroll
    for (int m = 0; m < 4; ++m)
#pragma unroll
      for (int nt = 0; nt < 4; ++nt) {
        float a0 = acc[m][nt][0], a1 = acc[m][nt][1], a2 = acc[m][nt][2], a3 = acc[m][nt][3];
        asm volatile("" : "+v"(a0), "+v"(a1), "+v"(a2), "+v"(a3));
        acc[m][nt][0] = a0; acc[m][nt][1] = a1; acc[m][nt][2] = a2; acc[m][nt][3] = a3;
      }
    __syncthreads();   // WAR: all waves done reading xT before next rep restages
  }

  // ---- epilogue (verbatim r8): cross-kq reduction, 2 rounds of m-pairs ----
#pragma unroll
  for (int r = 0; r < 2; ++r) {
    if (r) __syncthreads();
#pragma unroll
    for (int mm = 0; mm < 2; ++mm)
#pragma unroll
      for (int nt = 0; nt < 4; ++nt)
        *reinterpret_cast<f32x4*>(red + ((ph * 2 + mm) * 4 + kq) * 1024 +
                                  (nt * 16 + r16) * 16 + q * 4) = acc[2 * r + mm][nt];
    __syncthreads();
    {
      const int mm2 = kq >> 1;
      const int h = kq & 1;
      const float* base = red + (ph * 2 + mm2) * 4 * 1024;
#pragma unroll
      for (int nh = 0; nh < 2; ++nh) {
        int nt = h * 2 + nh;
        int off = (nt * 16 + r16) * 16 + q * 4;
        f32x4 ssum = *reinterpret_cast<const f32x4*>(base + off);
#pragma unroll
        for (int w = 1; w < 4; ++w)
          ssum += *reinterpret_cast<const f32x4*>(base + w * 1024 + off);
        long prow = pxbase + ph * 64 + (2 * r + mm2) * 16 + q * 4;
#pragma unroll
        for (int b = 0; b < 4; ++b)
          out[(prow + b) * 64 + nt * 16 + r16] = ssum[b];
      }
    }
  }
}

extern "C" void kernel_launch(void* const* d_in, const int* in_sizes, int n_in,
                              void* d_out, int out_size, void* d_ws, size_t ws_size,
                              hipStream_t stream) {
  const float* x = (const float*)d_in[0];
  const float* W = (const float*)d_in[1];
  float* out = (float*)d_out;
  unsigned short* Wp = (unsigned short*)d_ws;

  hipLaunchKernelGGL(wprep_kernel, dim3(576), dim3(256), 0, stream, W, Wp);
  // PROBE: single 8x-rep quad (~140 us) -> tops rocprof top-5 with real counters.
  hipLaunchKernelGGL(quad_rep, dim3(256), dim3(512), 0, stream, x, Wp, out);
}

// Round 13
// 23.582 us; speedup vs baseline: 18.0144x; 18.0144x over previous
//
#include <hip/hip_runtime.h>

typedef __attribute__((ext_vector_type(8))) short bf16x8;
typedef __attribute__((ext_vector_type(4))) float f32x4;

constexpr int NCH = 18;     // 32-k chunks per K-quarter (K = 2304 symmetrized)

__device__ __forceinline__ unsigned short bf_rne(float f) {
  unsigned u = __float_as_uint(f);
  return (unsigned short)((u + 0x7fffu + ((u >> 16) & 1u)) >> 16);
}

// ---- prepass: symmetrize + pack W fragment-linear (verbatim r5/r8, verified) ----
__global__ __launch_bounds__(256) void wprep_kernel(const float* __restrict__ W,
                                                    unsigned short* __restrict__ Wp) {
  int e = blockIdx.x * 256 + threadIdx.x;   // 576*256 = 147456
  int c = e & 2047;
  int t2 = e >> 11;
  int kq = t2 / 18;
  int j = t2 - kq * 18;
  int nt = c >> 9;
  int q = (c >> 7) & 3;
  int r16 = (c >> 3) & 15;
  int el = c & 7;
  int o = nt * 16 + r16;
  int kl = j * 32 + q * 8 + el;
  int jblk = kl >> 6, i = kl & 63;
  int run1 = 8 - kq;
  int G, F;
  if (jblk < run1) { G = 7 - kq; F = jblk; } else { G = kq; F = jblk - run1; }
  int f = F * 8 + (i >> 3), g = G * 8 + (i & 7);
  float v = W[o * 4096 + f * 64 + g];
  if (F != G) v += W[o * 4096 + g * 64 + f];
  Wp[e] = bf_rne(v);
}

// ---- main quad: r8 structure + PER-BLOCK J-ROTATION (de-lockstep the W sweep) ----
// 256 blocks x 512 thr (8 waves = 2 ph x 4 kq), 128 px/block.
__global__ __launch_bounds__(512, 2) void quad_kernel(const float* __restrict__ x,
                                                      const unsigned short* __restrict__ Wp,
                                                      float* __restrict__ out) {
  __shared__ float xT[8192];                 // [f 64][px 128], word = f*128 + (px^f)
  __shared__ alignas(16) float red[16384];   // 16 regions x 4 KB

  const int t = threadIdx.x;
  const int lane = t & 63;
  const int wv = t >> 6;        // 0..7
  const int kq = wv & 3;        // K quarter
  const int ph = wv >> 2;       // pixel half
  const int q = lane >> 4;
  const int r16 = lane & 15;
  const int pxbase = blockIdx.x * 128;
  const int j0 = blockIdx.x % NCH;           // rotation offset: de-lockstep W reads

  const char* wsrc = reinterpret_cast<const char*>(Wp) + kq * 73728 + lane * 16;
  const int run1 = 8 - kq;

  auto Gof = [&](int je) { return ((je >> 1) < run1) ? (7 - kq) : kq; };

  bf16x8 bufs[4][4];
  auto loadB = [&](int je, int slot) {
#pragma unroll
    for (int nt = 0; nt < 4; ++nt)
      bufs[slot][nt] = *reinterpret_cast<const bf16x8*>(wsrc + je * 4096 + nt * 1024);
  };
  // prologue: first 3 rotated chunks
  {
    int je = j0;
    loadB(je, 0); je = (je + 1 == NCH) ? 0 : je + 1;
    loadB(je, 1); je = (je + 1 == NCH) ? 0 : je + 1;
    loadB(je, 2);
  }

  // x tile -> xT (transposed, XOR word-swizzle; verified r3-r8)
  {
    const float* xg_ = x + (long)pxbase * 64;
#pragma unroll
    for (int c = 0; c < 4; ++c) {
      int e4 = c * 512 + t;
      int px = e4 >> 4;            // 0..127
      int f0 = (e4 & 15) * 4;
      float4 v = *reinterpret_cast<const float4*>(xg_ + e4 * 4);
      xT[(f0 + 0) * 128 + (px ^ (f0 + 0))] = v.x;
      xT[(f0 + 1) * 128 + (px ^ (f0 + 1))] = v.y;
      xT[(f0 + 2) * 128 + (px ^ (f0 + 2))] = v.z;
      xT[(f0 + 3) * 128 + (px ^ (f0 + 3))] = v.w;
    }
  }
  __syncthreads();

  float xg[4][8];
  auto load_xg = [&](int G) {
#pragma unroll
    for (int m = 0; m < 4; ++m) {
      int px = ph * 64 + m * 16 + r16;
#pragma unroll
      for (int b = 0; b < 8; ++b) {
        int row = G * 8 + b;
        xg[m][b] = xT[row * 128 + (px ^ row)];
      }
    }
  };
  int curG = Gof(j0);
  load_xg(curG);

  f32x4 acc[4][4] = {};   // [m: 4x16 px][nt: 4x16 o]

#pragma unroll
  for (int j = 0; j < NCH; ++j) {
    int je = j + j0;
    if (je >= NCH) je -= NCH;                    // rotated chunk index (wave-uniform)
    {
      int jp = je + 3;
      if (jp >= NCH) jp -= NCH;
      if (j + 3 < NCH) loadB(jp, (j + 3) & 3);   // 4-slot ring, lead = 3 bodies
    }
    int G = Gof(je);
    if (G != curG) { curG = G; load_xg(G); }     // wave-uniform, <=2 reloads total
    const int s = je & 1;
    const int blk = je >> 1;
    const int F = (blk < run1) ? blk : blk - run1;
    const int row = F * 8 + s * 4 + q;
    const int slot = j & 3;
    bf16x8 afr[4];
#pragma unroll
    for (int m = 0; m < 4; ++m) {
      float xf = xT[row * 128 + ((ph * 64 + m * 16 + r16) ^ row)];
      union { unsigned u[4]; bf16x8 v; } pk;
#pragma unroll
      for (int i = 0; i < 4; ++i) {
        unsigned p0 = __float_as_uint(xf * xg[m][2 * i]);
        unsigned p1 = __float_as_uint(xf * xg[m][2 * i + 1]);
        pk.u[i] = __builtin_amdgcn_perm(p1, p0, 0x07060302u);   // truncate-pack 2x bf16
      }
      afr[m] = pk.v;
    }
#pragma unroll
    for (int nt = 0; nt < 4; ++nt)
#pragma unroll
      for (int m = 0; m < 4; ++m)
        acc[m][nt] = __builtin_amdgcn_mfma_f32_16x16x32_bf16(afr[m], bufs[slot][nt],
                                                             acc[m][nt], 0, 0, 0);
  }

  // ---- cross-kq reduction (verbatim r8): 2 rounds of m-pairs ----
#pragma unroll
  for (int r = 0; r < 2; ++r) {
    if (r) __syncthreads();
#pragma unroll
    for (int mm = 0; mm < 2; ++mm)
#pragma unroll
      for (int nt = 0; nt < 4; ++nt)
        *reinterpret_cast<f32x4*>(red + ((ph * 2 + mm) * 4 + kq) * 1024 +
                                  (nt * 16 + r16) * 16 + q * 4) = acc[2 * r + mm][nt];
    __syncthreads();
    {
      const int mm2 = kq >> 1;
      const int h = kq & 1;
      const float* base = red + (ph * 2 + mm2) * 4 * 1024;
#pragma unroll
      for (int nh = 0; nh < 2; ++nh) {
        int nt = h * 2 + nh;
        int off = (nt * 16 + r16) * 16 + q * 4;
        f32x4 ssum = *reinterpret_cast<const f32x4*>(base + off);
#pragma unroll
        for (int w = 1; w < 4; ++w)
          ssum += *reinterpret_cast<const f32x4*>(base + w * 1024 + off);
        long prow = pxbase + ph * 64 + (2 * r + mm2) * 16 + q * 4;   // D: row=q*4+b, col=r16
#pragma unroll
        for (int b = 0; b < 4; ++b)
          out[(prow + b) * 64 + nt * 16 + r16] = ssum[b];
      }
    }
  }
}

extern "C" void kernel_launch(void* const* d_in, const int* in_sizes, int n_in,
                              void* d_out, int out_size, void* d_ws, size_t ws_size,
                              hipStream_t stream) {
  const float* x = (const float*)d_in[0];
  const float* W = (const float*)d_in[1];
  float* out = (float*)d_out;
  unsigned short* Wp = (unsigned short*)d_ws;   // 288 KB packed fragment-linear bf16 W

  hipLaunchKernelGGL(wprep_kernel, dim3(576), dim3(256), 0, stream, W, Wp);
  hipLaunchKernelGGL(quad_kernel, dim3(256), dim3(512), 0, stream, x, Wp, out);
}